// Round 8
// baseline (543.012 us; speedup 1.0000x reference)
//
#include <hip/hip_runtime.h>
#include <stdint.h>
#include <stddef.h>

#define IN_F 4096
#define OUT_F 4096
#define M_TOT 8192

// fused-fallback tile
#define BM 128
#define BN 128
#define BK 64

// main GEMM tile
#define BM2 256
#define BN2 256
#define BK2 64
#define NT2 (IN_F / BK2)   // 64 K-tiles

typedef __attribute__((ext_vector_type(8))) short short8;     // 8 x bf16 (4 VGPRs) MFMA A/B frag
typedef __attribute__((ext_vector_type(4))) float f32x4;      // 16x16 MFMA C/D frag
typedef __attribute__((ext_vector_type(16))) float f32x16;    // 32x32 MFMA C/D frag
typedef __attribute__((ext_vector_type(4))) float float4v;
typedef __attribute__((ext_vector_type(4))) unsigned short u16x4;
typedef __attribute__((ext_vector_type(8))) unsigned short u16x8;
typedef unsigned short u16;

// FP4 codebook (matches reference FP4_CODEBOOK exactly)
__constant__ float c_lut[16] = {
  0.0f, 0.0052f, 0.6667f, 1.0f, 0.3333f, 0.5f, 0.1667f, 0.25f,
  0.0f, -0.0052f, -0.6667f, -1.0f, -0.3333f, -0.5f, -0.1667f, -0.25f
};

// fp32 -> bf16 round-to-nearest-even
__device__ __forceinline__ u16 f2bf(float f) {
  unsigned int x = __float_as_uint(f);
  x += 0x7fffu + ((x >> 16) & 1u);
  return (u16)(x >> 16);
}

// async global->LDS, 16B per lane. LDS dest is wave-uniform base + lane*16.
__device__ __forceinline__ void gload_lds16(const u16* g, u16* lds) {
  __builtin_amdgcn_global_load_lds(
      (const __attribute__((address_space(1))) unsigned int*)g,
      (__attribute__((address_space(3))) unsigned int*)lds, 16, 0, 0);
}

// raw barrier; counted waits handle data deps (no full drain in steady state).
#define BARRIER() do { asm volatile("" ::: "memory"); \
                       __builtin_amdgcn_s_barrier();  \
                       asm volatile("" ::: "memory"); } while (0)
// counted lgkm wait + scheduler pin (rule #18: stops MFMA hoisting past the wait)
#define LGW(n) do { asm volatile("s_waitcnt lgkmcnt(" #n ")" ::: "memory"); \
                    __builtin_amdgcn_sched_barrier(0); } while (0)
#define VMW(n) asm volatile("s_waitcnt vmcnt(" #n ")" ::: "memory")

// ---------------- merged prep: W dequant (blocks 0..511) + x convert ----------------
__global__ __launch_bounds__(256) void k_prep(const float* __restrict__ x,
                                              u16* __restrict__ a,
                                              const int* __restrict__ wp,
                                              const float* __restrict__ scale,
                                              u16* __restrict__ b) {
  if (blockIdx.x < 512) {
    __shared__ float lut[16];
    if (threadIdx.x < 16) lut[threadIdx.x] = c_lut[threadIdx.x];
    __syncthreads();
    const int ng = (OUT_F * IN_F / 2) / 4;  // int4 groups
    const int stride = 512 * 256;
    for (int t = blockIdx.x * 256 + threadIdx.x; t < ng; t += stride) {
      int4 p = ((const int4*)wp)[t];
      float s = scale[t >> 3];
      int by[4] = {p.x, p.y, p.z, p.w};
      u16x8 o;
#pragma unroll
      for (int q = 0; q < 4; ++q) {
        o[2 * q]     = f2bf(lut[(by[q] >> 4) & 15] * s);
        o[2 * q + 1] = f2bf(lut[by[q] & 15] * s);
      }
      ((u16x8*)b)[t] = o;
    }
  } else {
    const int n8 = (M_TOT * IN_F) / 8;
    const int stride = 4096 * 256;
    for (int t = (blockIdx.x - 512) * 256 + threadIdx.x; t < n8; t += stride) {
      float4v f0 = ((const float4v*)x)[2 * t];
      float4v f1 = ((const float4v*)x)[2 * t + 1];
      u16x8 o;
      o[0] = f2bf(f0.x); o[1] = f2bf(f0.y); o[2] = f2bf(f0.z); o[3] = f2bf(f0.w);
      o[4] = f2bf(f1.x); o[5] = f2bf(f1.y); o[6] = f2bf(f1.z); o[7] = f2bf(f1.w);
      ((u16x8*)a)[t] = o;
    }
  }
}

// ===================== 256x256 pipelined GEMM (r3 schedule, 32x32x16 MFMA) =====================
// C = A(bf16, MxK) * B(bf16, NxK)^T + bias. 512 thr / 8 waves (2M x 4N),
// per-wave output 128x64 = acc[4][2] of 32x32 f32x16 frags.
// SCHEDULE = ROUND-3 BEST (264us / 46.5% MfmaUtil), now with staging restored
// VERBATIM (r6 had wrongly used the r2 staging layout -> tile1 B never staged
// -> uninitialized-LDS reads -> absmax inf):
//   reads:   P1: b0_t, b1_t   P2: aN_t   P4: aC_{t+1}
//   LGW:     P1: 4            P2: 8      P3: 8 (0 last)   P4: none
//   staging: P1: B0_{t+1}->other(x2)  P2: B1_{t+1}->other(x2)
//            P3: A1_{t+1}->other(x2)  P4: A0_{t+2}->cur(x2)
//   VMW:     P1: 6 (0 at last tile)   P3: 2
// ONLY intended delta vs r3: 8 x (32x32x16) MFMA per phase instead of
// 16 x (16x16x32). Measured ceilings 2382 vs 2075 TF (+15% compute floor).
// Frag maps: A/B row(col)=lane&31, k=(lane>>5)*8+[0..7] contiguous (exact
// analog of our verified 16x16x32 map row=lane&15, k=(lane>>4)*8); C/D
// col=lane&31, row=(reg&3)+8*(reg>>2)+4*(lane>>5)  [m74/m101-verified].
// LDS chunk-XOR swizzle: LDS 16B-chunk p of row r holds GLOBAL chunk p^(r&7);
// read chunk ((ks*2)+(lane>>5))^(arow&7) = (ks*2)^hx, hx=(lane>>5)^(arow&7).

__device__ __forceinline__ void st_b(const u16* __restrict__ B, u16* dst,
                                     int nBase, int kt, int h, int k,
                                     int wave, int srow, int scol) {
  const int r0 = 64 * (wave >> 1) + 32 * h + 16 * k + 8 * (wave & 1);
  gload_lds16(B + (size_t)(nBase + r0 + srow) * IN_F + kt + scol, dst + r0 * BK2);
}
__device__ __forceinline__ void st_a(const u16* __restrict__ A, u16* dst,
                                     int mBase, int kt, int h, int k,
                                     int wave, int srow, int scol) {
  const int r0 = 128 * (wave >> 2) + 64 * h + 32 * k + 8 * (wave & 3);
  gload_lds16(A + (size_t)(mBase + r0 + srow) * IN_F + kt + scol, dst + r0 * BK2);
}

// 4 x ds_read_b128: one 32-col B block (jhOff = jh*32*BK2), k-steps 0..3
__device__ __forceinline__ void rd_b32(short8 d[4], const u16* Bs_c,
                                       int bOff, int jhOff, int hx) {
#pragma unroll
  for (int ks = 0; ks < 4; ++ks)
    d[ks] = *(const short8*)&Bs_c[bOff + jhOff + (((ks * 2) ^ hx) << 3)];
}
// 8 x ds_read_b128: one 64-row A half (hOff = h*64*BK2), 2 row-blocks x 4 k-steps
__device__ __forceinline__ void rd_a32(short8 d[2][4], const u16* As_c,
                                       int aOff, int hOff, int hx) {
#pragma unroll
  for (int rb = 0; rb < 2; ++rb)
#pragma unroll
    for (int ks = 0; ks < 4; ++ks)
      d[rb][ks] = *(const short8*)&As_c[aOff + hOff + rb * (32 * BK2) +
                                        (((ks * 2) ^ hx) << 3)];
}
// one quadrant: 8 x v_mfma_f32_32x32x16_bf16 (2 acc chains x 4 k-steps)
__device__ __forceinline__ void mma32(f32x16 acc[4][2], const short8 a[2][4],
                                      const short8 b[4], int h, int jh) {
#pragma unroll
  for (int ks = 0; ks < 4; ++ks)
#pragma unroll
    for (int rb = 0; rb < 2; ++rb)
      acc[h * 2 + rb][jh] = __builtin_amdgcn_mfma_f32_32x32x16_bf16(
          a[rb][ks], b[ks], acc[h * 2 + rb][jh], 0, 0, 0);
}

__global__ __launch_bounds__(512, 2) void k_gemm256(const u16* __restrict__ A,
                                                    const u16* __restrict__ B,
                                                    const float* __restrict__ bias,
                                                    float* __restrict__ C) {
  __shared__ u16 As[2][BM2 * BK2];   // 2 x 32 KiB
  __shared__ u16 Bs[2][BN2 * BK2];   // 2 x 32 KiB

  const int tid  = threadIdx.x;
  const int lane = tid & 63;
  const int wave = tid >> 6;

  // XCD-aware tile swizzle: 8x8 tile square per XCD (grid 32x16 = 512, %8==0)
  const int bid   = blockIdx.x;
  const int xcd   = bid & 7;
  const int kk    = bid >> 3;
  const int tileM = (xcd >> 1) * 8 + (kk >> 3);
  const int tileN = (xcd & 1) * 8 + (kk & 7);
  const int mBase = tileM * BM2;
  const int nBase = tileN * BN2;

  const int wm = (wave >> 2) * 128;
  const int wn = (wave & 3) * 64;

  // staging lane decomposition (8 rows x 64 cols per gload, XOR-swizzled source)
  const int srow = lane >> 3;
  const int scol = ((lane & 7) ^ srow) * 8;

  // 32x32 MFMA operand addressing
  const int arow = lane & 31;                 // A row / B col within block
  const int hx   = (lane >> 5) ^ (arow & 7);  // k-chunk xor key (swizzle folded)
  const int aOff = (wm + arow) * BK2;
  const int bOff = (wn + arow) * BK2;

  f32x16 acc[4][2] = {};
  short8 aC[2][4], aN[2][4], b0[4], b1[4];

#define SA(dst, t, h, k) st_a(A, dst, mBase, (t) * BK2, h, k, wave, srow, scol)
#define SB(dst, t, h, k) st_b(B, dst, nBase, (t) * BK2, h, k, wave, srow, scol)

  // ---- prologue (= r3): tile0 {A0,B0,B1,A1} (8 rounds) + A0_1 (2 rounds) ----
  SA(As[0], 0, 0, 0); SA(As[0], 0, 0, 1);
  SB(Bs[0], 0, 0, 0); SB(Bs[0], 0, 0, 1);
  SB(Bs[0], 0, 1, 0); SB(Bs[0], 0, 1, 1);
  SA(As[0], 0, 1, 0); SA(As[0], 0, 1, 1);
  SA(As[1], 1, 0, 0); SA(As[1], 1, 0, 1);
  VMW(2);            // tile0's 8 rounds landed; A0_1 pair stays in flight
  BARRIER();
  rd_a32(aC, As[0], aOff, 0, hx);        // lgkm queue: [aC 8]

  for (int t = 0; t < NT2; ++t) {
    const int c = t & 1;
    u16* AsC = As[c];
    u16* BsC = Bs[c];
    u16* AsO = As[c ^ 1];
    u16* BsO = Bs[c ^ 1];

    // ---------- P1: MFMA aC x b0 ----------
    if (t < NT2 - 1) { VMW(6); } else { VMW(0); }   // drain B0_t stage rounds
    rd_b32(b0, BsC, bOff, 0, hx);                   // b0_t
    __builtin_amdgcn_sched_barrier(0);              // pin: b0 group older than b1
    rd_b32(b1, BsC, bOff, 32 * BK2, hx);            // b1_t (kept in flight)
    if (t + 1 < NT2) {                              // stage B0_{t+1} -> other buf
      SB(BsO, t + 1, 0, 0); SB(BsO, t + 1, 0, 1);
    }
    BARRIER();
    LGW(4);                                         // aC_t + b0_t done; b1 flying
    __builtin_amdgcn_s_setprio(1);
    mma32(acc, aC, b0, 0, 0);
    __builtin_amdgcn_s_setprio(0);

    // ---------- P2: MFMA aC x b1 ----------
    rd_a32(aN, AsC, aOff, 64 * BK2, hx);            // aN_t (kept in flight)
    if (t + 1 < NT2) {                              // stage B1_{t+1} -> other buf
      SB(BsO, t + 1, 1, 0); SB(BsO, t + 1, 1, 1);
    }
    BARRIER();
    LGW(8);                                         // b1 done; aN flying
    __builtin_amdgcn_s_setprio(1);
    mma32(acc, aC, b1, 0, 1);
    __builtin_amdgcn_s_setprio(0);

    // ---------- P3: MFMA aN x b1 ----------
    VMW(2);                                         // drain older stage rounds
    if (t + 1 < NT2) {                              // stage A1_{t+1} -> other buf
      SA(AsO, t + 1, 1, 0); SA(AsO, t + 1, 1, 1);
    }
    BARRIER();
    if (t + 1 < NT2) { LGW(8); } else { LGW(0); }   // drain aN_t
    __builtin_amdgcn_s_setprio(1);
    mma32(acc, aN, b1, 1, 1);
    __builtin_amdgcn_s_setprio(0);

    // ---------- P4: MFMA aN x b0 ----------
    if (t + 1 < NT2) rd_a32(aC, AsO, aOff, 0, hx);  // aC_{t+1} (flying)
    if (t + 2 < NT2) {                              // stage A0_{t+2} -> cur buf
      SA(AsC, t + 2, 0, 0); SA(AsC, t + 2, 0, 1);
    }
    BARRIER();
    __builtin_amdgcn_sched_barrier(0);              // deps drained at P1/P3
    __builtin_amdgcn_s_setprio(1);
    mma32(acc, aN, b0, 1, 0);
    __builtin_amdgcn_s_setprio(0);
  }

#undef SA
#undef SB

  // epilogue: 32x32 C/D layout: col = lane&31, row = (reg&3)+8*(reg>>2)+4*(lane>>5)
  const int ccol = lane & 31;
  const int rhi  = (lane >> 5) * 4;
#pragma unroll
  for (int j = 0; j < 2; ++j) {
    const int col = nBase + wn + j * 32 + ccol;
    const float bv = bias[col];
#pragma unroll
    for (int i = 0; i < 4; ++i) {
      const int rbase = mBase + wm + i * 32 + rhi;
#pragma unroll
      for (int reg = 0; reg < 16; ++reg) {
        const int row = rbase + (reg & 3) + 8 * (reg >> 2);
        C[(size_t)row * OUT_F + col] = acc[i][j][reg] + bv;
      }
    }
  }
}

// -------- fallback: fully fused (no workspace), register-staged conversion --------
__global__ __launch_bounds__(256) void k_gemm_fused(const float* __restrict__ X,
                                                    const int* __restrict__ WP,
                                                    const float* __restrict__ scale,
                                                    const float* __restrict__ bias,
                                                    float* __restrict__ C) {
  __shared__ u16 As[BM * BK];
  __shared__ u16 Bs[BN * BK];
  __shared__ float lut[16];
  const int tid = threadIdx.x;
  if (tid < 16) lut[tid] = c_lut[tid];
  const int lane = tid & 63;
  const int wave = tid >> 6;
  const int mBase = blockIdx.y * BM;
  const int nBase = blockIdx.x * BN;
  const int wm = (wave >> 1) * 64;
  const int wn = (wave & 1) * 64;
  const int frow = lane & 15;
  const int fx   = lane & 7;
  const int cq   = lane >> 4;
  f32x4 acc[4][4] = {};
  __syncthreads();  // lut ready

  for (int kt = 0; kt < IN_F; kt += BK) {
#pragma unroll
    for (int i = 0; i < 8; ++i) {
      const int g = tid + i * 256;
      const int r = g >> 4, c = (g & 15) * 4;
      float4v f = *(const float4v*)&X[(size_t)(mBase + r) * IN_F + kt + c];
      u16x4 o;
      o.x = f2bf(f.x); o.y = f2bf(f.y); o.z = f2bf(f.z); o.w = f2bf(f.w);
      *(u16x4*)&As[r * BK + ((((c >> 3) ^ (r & 7)) << 3) | (c & 7))] = o;
    }
#pragma unroll
    for (int i = 0; i < 4; ++i) {
      const int g = tid + i * 256;
      const int r = g >> 3, c4 = (g & 7) * 4;
      int4 p = *(const int4*)&WP[(size_t)(nBase + r) * (IN_F / 2) + (kt >> 1) + c4];
      const float s = scale[(nBase + r) * 64 + (kt >> 6)];
      int by[4] = {p.x, p.y, p.z, p.w};
      u16x8 o;
#pragma unroll
      for (int q = 0; q < 4; ++q) {
        o[2 * q]     = f2bf(lut[(by[q] >> 4) & 15] * s);
        o[2 * q + 1] = f2bf(lut[by[q] & 15] * s);
      }
      *(u16x8*)&Bs[r * BK + (((g & 7) ^ (r & 7)) << 3)] = o;
    }
    __syncthreads();
#pragma unroll
    for (int ks = 0; ks < BK; ks += 32) {
      const int co = (((ks >> 3) + cq) ^ fx) << 3;
      short8 a[4], b[4];
#pragma unroll
      for (int i = 0; i < 4; ++i)
        a[i] = *(const short8*)&As[(wm + i * 16 + frow) * BK + co];
#pragma unroll
      for (int j = 0; j < 4; ++j)
        b[j] = *(const short8*)&Bs[(wn + j * 16 + frow) * BK + co];
#pragma unroll
      for (int i = 0; i < 4; ++i)
#pragma unroll
        for (int j = 0; j < 4; ++j)
          acc[i][j] = __builtin_amdgcn_mfma_f32_16x16x32_bf16(a[i], b[j], acc[i][j], 0, 0, 0);
    }
    __syncthreads();
  }

  const int ccol = lane & 15;
  const int crow = (lane >> 4) * 4;
#pragma unroll
  for (int j = 0; j < 4; ++j) {
    const int col = nBase + wn + j * 16 + ccol;
    const float bv = bias[col];
#pragma unroll
    for (int i = 0; i < 4; ++i) {
      const size_t rb = (size_t)(mBase + wm + i * 16 + crow) * OUT_F + col;
#pragma unroll
      for (int t = 0; t < 4; ++t)
        C[rb + (size_t)t * OUT_F] = acc[i][j][t] + bv;
    }
  }
}

extern "C" void kernel_launch(void* const* d_in, const int* in_sizes, int n_in,
                              void* d_out, int out_size, void* d_ws, size_t ws_size,
                              hipStream_t stream) {
  const float* x  = (const float*)d_in[0];
  const int*   wp = (const int*)d_in[1];
  const float* sc = (const float*)d_in[2];
  const float* bi = (const float*)d_in[3];
  float* out = (float*)d_out;

  const size_t bBytes = (size_t)OUT_F * IN_F * 2;   // 33.5 MB bf16 W
  const size_t aBytes = (size_t)M_TOT * IN_F * 2;   // 67 MB bf16 x

  if (ws_size >= aBytes + bBytes) {
    u16* B = (u16*)d_ws;
    u16* A = (u16*)((char*)d_ws + bBytes);
    k_prep<<<4608, 256, 0, stream>>>(x, A, wp, sc, B);
    k_gemm256<<<(M_TOT / BM2) * (OUT_F / BN2), 512, 0, stream>>>(A, B, bi, out);
  } else {
    dim3 grid(OUT_F / BN, M_TOT / BM);
    k_gemm_fused<<<grid, 256, 0, stream>>>(x, wp, sc, bi, out);
  }
}